// Round 6
// baseline (425.660 us; speedup 1.0000x reference)
//
#include <hip/hip_runtime.h>

#define T_TOK 2048
#define HID   2048
#define INTER 768
#define NE    32
#define NSLOT 8192   // T_TOK * TOP_K
#define MAXT  96     // max (expert, mt) tiles at BM=128

typedef short bf16x8 __attribute__((ext_vector_type(8)));
typedef float f32x4  __attribute__((ext_vector_type(4)));

__device__ __forceinline__ unsigned short f2b(float f){
  unsigned u = __builtin_bit_cast(unsigned, f);
  u += 0x7fffu + ((u >> 16) & 1u);      // RNE
  return (unsigned short)(u >> 16);
}
__device__ __forceinline__ unsigned pk2(float a, float b){
  return (unsigned)f2b(a) | ((unsigned)f2b(b) << 16);
}

// ---------------- workspace layout (bytes) ----------------
#define XB_OFF    0ul
#define HBUF_OFF  8388608ul
#define TKW_OFF   20971520ul
#define TKI_OFF   21004288ul
#define ROWS_OFF  21037056ul
#define WTS_OFF   21069824ul
#define OFFS_OFF  21102592ul
#define LOGIT_OFF 21102848ul
#define CNT_OFF   21364992ul
#define FILL_OFF  21365120ul
#define TLIST_OFF 21365248ul
#define T2S_OFF   21365760ul
#define HB2_OFF   21398528ul
#define WS_NEED   (HB2_OFF + 67108864ul)
#define ZERO_OFF  21102848ul
#define ZERO_SZ   (262144ul + 128ul + 128ul)

// ---------------- x fp32 -> bf16 ----------------
__global__ void convert_x_kernel(const float* __restrict__ x, ushort* __restrict__ xb){
  int i = (blockIdx.x * 256 + threadIdx.x) * 8;
  float4 a = *(const float4*)(x + i);
  float4 b = *(const float4*)(x + i + 4);
  uint4 o;
  o.x = pk2(a.x, a.y);
  o.y = pk2(a.z, a.w);
  o.z = pk2(b.x, b.y);
  o.w = pk2(b.z, b.w);
  *(uint4*)(xb + i) = o;
}

// ---------------- router logits (fp32 GEMM, split-K atomic) ----------------
__global__ void router_gemm(const float* __restrict__ x, const float* __restrict__ wr,
                            float* __restrict__ logits){
  const int tt = blockIdx.x;
  const int kb = blockIdx.y;
  __shared__ float xs[64 * 64];
  __shared__ float wsm[64 * 32];
  const int tid = threadIdx.x;
  const int r = tid >> 5, e = tid & 31;
  float acc[8];
#pragma unroll
  for (int i = 0; i < 8; i++) acc[i] = 0.0f;

  for (int sub = 0; sub < 4; ++sub){
    const int k0 = kb * 256 + sub * 64;
    __syncthreads();
#pragma unroll
    for (int j = 0; j < 4; j++){
      int f4 = tid + j * 256;
      int row = f4 >> 4, c4 = f4 & 15;
      float4 v = *(const float4*)(x + (size_t)(tt * 64 + row) * HID + k0 + c4 * 4);
      *(float4*)(xs + row * 64 + c4 * 4) = v;
    }
#pragma unroll
    for (int j = 0; j < 2; j++){
      int f4 = tid + j * 256;
      int row = f4 >> 3, c4 = f4 & 7;
      float4 v = *(const float4*)(wr + (size_t)(k0 + row) * NE + c4 * 4);
      *(float4*)(wsm + row * NE + c4 * 4) = v;
    }
    __syncthreads();
    for (int kk = 0; kk < 64; kk++){
      float wv = wsm[kk * NE + e];
#pragma unroll
      for (int i = 0; i < 8; i++) acc[i] += xs[(r + i * 8) * 64 + kk] * wv;
    }
  }
#pragma unroll
  for (int i = 0; i < 8; i++)
    atomicAdd(&logits[(size_t)(tt * 64 + r + i * 8) * NE + e], acc[i]);
}

// ---------------- softmax + top-4 + renorm + counts ----------------
__global__ void topk_kernel(const float* __restrict__ logits, float* __restrict__ topk_w,
                            int* __restrict__ topk_i, int* __restrict__ counts){
  int t = blockIdx.x * blockDim.x + threadIdx.x;
  if (t >= T_TOK) return;
  float l[32];
  const float4* lp = (const float4*)(logits + (size_t)t * NE);
#pragma unroll
  for (int i = 0; i < 8; i++){
    float4 v = lp[i];
    l[i*4+0] = v.x; l[i*4+1] = v.y; l[i*4+2] = v.z; l[i*4+3] = v.w;
  }
  float m = l[0];
#pragma unroll
  for (int i = 1; i < 32; i++) m = fmaxf(m, l[i]);
#pragma unroll
  for (int i = 0; i < 32; i++) l[i] = __expf(l[i] - m);
  float wsel[4]; int isel[4];
#pragma unroll
  for (int k = 0; k < 4; k++){
    float best = l[0]; int bi = 0;
#pragma unroll
    for (int i = 1; i < 32; i++){ if (l[i] > best){ best = l[i]; bi = i; } }
    wsel[k] = best; isel[k] = bi; l[bi] = -1.0f;
  }
  float s4 = wsel[0] + wsel[1] + wsel[2] + wsel[3];
  float inv = 1.0f / s4;
#pragma unroll
  for (int k = 0; k < 4; k++){
    topk_w[t * 4 + k] = wsel[k] * inv;
    topk_i[t * 4 + k] = isel[k];
    atomicAdd(&counts[isel[k]], 1);
  }
}

__global__ void prefix_kernel(const int* __restrict__ counts, int* __restrict__ offsets,
                              int* __restrict__ tlist){
  if (threadIdx.x == 0){
    int a = 0; offsets[0] = 0; int nt_ = 0;
    for (int e = 0; e < NE; e++){
      int c = counts[e];
      for (int m = 0; m * 128 < c && nt_ < MAXT; m++) tlist[nt_++] = e | (m << 16);
      a += c; offsets[e + 1] = a;
    }
    for (; nt_ < MAXT; nt_++) tlist[nt_] = -1;
  }
}

__global__ void scatter_kernel(const int* __restrict__ topk_i, const float* __restrict__ topk_w,
                               const int* __restrict__ offsets, int* __restrict__ fill,
                               int* __restrict__ rows, float* __restrict__ wts,
                               int* __restrict__ t2s){
  int gid = blockIdx.x * 256 + threadIdx.x;
  int t = gid >> 2;
  int e = topk_i[gid];
  int pos = atomicAdd(&fill[e], 1);
  int s = offsets[e] + pos;
  rows[s] = t;
  wts[s] = topk_w[gid];
  t2s[gid] = s;
}

// ---------------- gate+up GEMM ----------------
// BM=128, BN=128 (per matrix, gate+up both), BK=32, 64 K-steps, 512 threads
// (8 waves = 4m x 2n). Each block reads 512 B of every weight row (vs 256 B
// before) to improve HBM row-buffer locality — round-5 theory: 2.6 TB/s cap
// came from 256-B/3KB-row touches. LDS: padded col stride 40 ushorts (2-way
// bank conflicts max, balanced). 2-phase prefetch, double buffered (60 KB).
#define NT_GU 64
#define GU_STRIDE 15360   // ushorts per buffer: A 5120 + Bg 5120 + Bu 5120
__global__ __launch_bounds__(512) void gateup_kernel(
    const ushort* __restrict__ xb, const float* __restrict__ wg,
    const float* __restrict__ wu, const int* __restrict__ rows,
    const float* __restrict__ wts, const int* __restrict__ counts,
    const int* __restrict__ offsets, const int* __restrict__ tlist,
    ushort* __restrict__ hbuf)
{
  const int w = tlist[blockIdx.y];
  if (w < 0) return;
  const int e = w & 0xffff, mt = w >> 16;
  const int nt = blockIdx.x;          // 0..5
  const int cnt = counts[e];
  const int off = offsets[e];
  const int n0 = nt * 128;

  __shared__ __align__(16) ushort lds[2 * GU_STRIDE];  // 61440 B

  const int tid = threadIdx.x;

  // A staging: one 16-B chunk per thread (128 rows x 32 k bf16 = 8 KB)
  const int arow = tid >> 2, ablk = tid & 3;
  const int srow = mt * 128 + arow;
  const int tokA = rows[off + (srow < cnt ? srow : 0)];
  const ushort* agp = xb + (size_t)tokA * HID + ablk * 8;
  const int adst = arow * 40 + ablk * 8;

  // B staging: thread owns one col, 8 k's per matrix (strided dwords)
  const int bcol = tid & 127, bkg = tid >> 7;   // bkg 0..3
  const size_t wofs = (size_t)e * (HID * INTER) + (size_t)bkg * 8 * INTER + n0 + bcol;
  const float* wgp = wg + wofs;
  const float* wup = wu + wofs;
  const int bdst = bcol * 40 + bkg * 8;

  // compute roles: 4m x 2n waves
  const int lane = tid & 63, wv = tid >> 6;
  const int wm = wv >> 1, wn = wv & 1;
  const int fr = lane & 15, ko = lane >> 4;

  f32x4 accg[2][4], accu[2][4];
#pragma unroll
  for (int i = 0; i < 2; i++)
#pragma unroll
    for (int j = 0; j < 4; j++){ accg[i][j] = (f32x4)(0.0f); accu[i][j] = (f32x4)(0.0f); }

  uint4 pa;
  float sg[8], su[8];

  auto loadSet = [&](int k0){
    pa = *(const uint4*)(agp + k0);
    const float* pg_ = wgp + (size_t)k0 * INTER;
    const float* pu_ = wup + (size_t)k0 * INTER;
#pragma unroll
    for (int kk = 0; kk < 8; kk++){ sg[kk] = pg_[(size_t)kk * INTER]; su[kk] = pu_[(size_t)kk * INTER]; }
  };
  auto writeSet = [&](int base){
    *(uint4*)(lds + base + adst) = pa;
    uint4 pg, pu;
    pg.x = pk2(sg[0], sg[1]); pg.y = pk2(sg[2], sg[3]);
    pg.z = pk2(sg[4], sg[5]); pg.w = pk2(sg[6], sg[7]);
    pu.x = pk2(su[0], su[1]); pu.y = pk2(su[2], su[3]);
    pu.z = pk2(su[4], su[5]); pu.w = pk2(su[6], su[7]);
    *(uint4*)(lds + base + 5120 + bdst)  = pg;
    *(uint4*)(lds + base + 10240 + bdst) = pu;
  };
  auto computeTile = [&](int base){
    const ushort* A  = lds + base;
    const ushort* BG = lds + base + 5120;
    const ushort* BU = lds + base + 10240;
    bf16x8 a[2], bg2[4], bu2[4];
#pragma unroll
    for (int mf = 0; mf < 2; mf++)
      a[mf] = *(const bf16x8*)(A + (wm * 32 + mf * 16 + fr) * 40 + ko * 8);
#pragma unroll
    for (int nf = 0; nf < 4; nf++){
      bg2[nf] = *(const bf16x8*)(BG + (wn * 64 + nf * 16 + fr) * 40 + ko * 8);
      bu2[nf] = *(const bf16x8*)(BU + (wn * 64 + nf * 16 + fr) * 40 + ko * 8);
    }
#pragma unroll
    for (int mf = 0; mf < 2; mf++)
#pragma unroll
      for (int nf = 0; nf < 4; nf++){
        accg[mf][nf] = __builtin_amdgcn_mfma_f32_16x16x32_bf16(a[mf], bg2[nf], accg[mf][nf], 0, 0, 0);
        accu[mf][nf] = __builtin_amdgcn_mfma_f32_16x16x32_bf16(a[mf], bu2[nf], accu[mf][nf], 0, 0, 0);
      }
  };

  loadSet(0);
  writeSet(0);
  __syncthreads();

  int cbase = 0;
  for (int t = 0; t < NT_GU; ++t){
    const int nb = cbase ^ GU_STRIDE;
    if (t + 1 < NT_GU) loadSet((t + 1) * 32);
    computeTile(cbase);
    if (t + 1 < NT_GU) writeSet(nb);
    __syncthreads();
    cbase = nb;
  }

  // epilogue
#pragma unroll
  for (int mf = 0; mf < 2; mf++)
#pragma unroll
    for (int j = 0; j < 4; j++){
      int rl = wm * 32 + mf * 16 + ko * 4 + j;
      int gr = mt * 128 + rl;
      if (gr < cnt){
        float w2 = wts[off + gr];
        size_t robase = (size_t)(off + gr) * INTER + n0;
#pragma unroll
        for (int nf = 0; nf < 4; nf++){
          float g = accg[mf][nf][j], u = accu[mf][nf][j];
          float h = (g / (1.0f + __expf(-g))) * u * w2;
          hbuf[robase + wn * 64 + nf * 16 + fr] = f2b(h);
        }
      }
    }
}

// ---------------- down GEMM ----------------
// BM=128, BN=256, BK=32, 24 K-steps, 512 threads (8 waves = 2m x 4n).
// Each block reads 1 KB of every wd row (8 KB rows) for HBM row locality.
#define NT_DN 24
#define DN_STRIDE 15360   // A 5120 + B 10240
template<bool SLOT>
__global__ __launch_bounds__(512) void down_kernel(
    const ushort* __restrict__ hbuf, const float* __restrict__ wd,
    const int* __restrict__ rows, const int* __restrict__ counts,
    const int* __restrict__ offsets, const int* __restrict__ tlist,
    float* __restrict__ outp)
{
  const int w = tlist[blockIdx.y];
  if (w < 0) return;
  const int e = w & 0xffff, mt = w >> 16;
  const int nt = blockIdx.x;          // 0..7
  const int cnt = counts[e];
  const int off = offsets[e];
  const int n0 = nt * 256;

  __shared__ __align__(16) ushort lds[2 * DN_STRIDE];  // 61440 B

  const int tid = threadIdx.x;

  // A staging
  const int arow = tid >> 2, ablk = tid & 3;
  const int srow = mt * 128 + arow;
  const int slotA = off + (srow < cnt ? srow : 0);
  const ushort* agp = hbuf + (size_t)slotA * INTER + ablk * 8;
  const int adst = arow * 40 + ablk * 8;

  // B staging: thread owns one col, 16 k's (strided dwords)
  const int bcol = tid & 255, bkg = tid >> 8;   // bkg 0..1
  const float* wdp = wd + (size_t)e * (INTER * HID) + (size_t)bkg * 16 * HID + n0 + bcol;
  const int bdst = 5120 + bcol * 40 + bkg * 16;

  // compute roles: 2m x 4n waves
  const int lane = tid & 63, wv = tid >> 6;
  const int wm = wv >> 2, wn = wv & 3;
  const int fr = lane & 15, ko = lane >> 4;

  f32x4 acc[4][4];
#pragma unroll
  for (int i = 0; i < 4; i++)
#pragma unroll
    for (int j = 0; j < 4; j++) acc[i][j] = (f32x4)(0.0f);

  uint4 pa;
  float sb[16];

  auto loadSet = [&](int k0){
    pa = *(const uint4*)(agp + k0);
    const float* p = wdp + (size_t)k0 * HID;
#pragma unroll
    for (int kk = 0; kk < 16; kk++) sb[kk] = p[(size_t)kk * HID];
  };
  auto writeSet = [&](int base){
    *(uint4*)(lds + base + adst) = pa;
    uint4 p0, p1;
    p0.x = pk2(sb[0], sb[1]);  p0.y = pk2(sb[2], sb[3]);
    p0.z = pk2(sb[4], sb[5]);  p0.w = pk2(sb[6], sb[7]);
    p1.x = pk2(sb[8], sb[9]);  p1.y = pk2(sb[10], sb[11]);
    p1.z = pk2(sb[12], sb[13]); p1.w = pk2(sb[14], sb[15]);
    *(uint4*)(lds + base + bdst)     = p0;
    *(uint4*)(lds + base + bdst + 8) = p1;
  };
  auto computeTile = [&](int base){
    const ushort* A = lds + base;
    const ushort* B = lds + base + 5120;
    bf16x8 a[4], b2[4];
#pragma unroll
    for (int mf = 0; mf < 4; mf++)
      a[mf] = *(const bf16x8*)(A + (wm * 64 + mf * 16 + fr) * 40 + ko * 8);
#pragma unroll
    for (int nf = 0; nf < 4; nf++)
      b2[nf] = *(const bf16x8*)(B + (wn * 64 + nf * 16 + fr) * 40 + ko * 8);
#pragma unroll
    for (int mf = 0; mf < 4; mf++)
#pragma unroll
      for (int nf = 0; nf < 4; nf++)
        acc[mf][nf] = __builtin_amdgcn_mfma_f32_16x16x32_bf16(a[mf], b2[nf], acc[mf][nf], 0, 0, 0);
  };

  loadSet(0);
  writeSet(0);
  __syncthreads();

  int cbase = 0;
  for (int t = 0; t < NT_DN; ++t){
    const int nb = cbase ^ DN_STRIDE;
    if (t + 1 < NT_DN) loadSet((t + 1) * 32);
    computeTile(cbase);
    if (t + 1 < NT_DN) writeSet(nb);
    __syncthreads();
    cbase = nb;
  }

#pragma unroll
  for (int mf = 0; mf < 4; mf++)
#pragma unroll
    for (int j = 0; j < 4; j++){
      int rl = wm * 64 + mf * 16 + ko * 4 + j;
      int gr = mt * 128 + rl;
      if (gr < cnt){
        if (SLOT){
          float* obase = outp + (size_t)(off + gr) * HID + n0;
#pragma unroll
          for (int nf = 0; nf < 4; nf++)
            obase[wn * 64 + nf * 16 + fr] = acc[mf][nf][j];
        } else {
          int tok = rows[off + gr];
          float* obase = outp + (size_t)tok * HID + n0;
#pragma unroll
          for (int nf = 0; nf < 4; nf++)
            atomicAdd(obase + wn * 64 + nf * 16 + fr, acc[mf][nf][j]);
        }
      }
    }
}

// ---------------- combine: out[t] = sum of token t's 4 slot rows ----------------
__global__ void combine_kernel(const float* __restrict__ hbuf2, const int* __restrict__ t2s,
                               float* __restrict__ out){
  const int t = blockIdx.y;
  const int c4 = (blockIdx.x * 256 + threadIdx.x) * 4;
  const int s0 = t2s[t * 4 + 0], s1 = t2s[t * 4 + 1];
  const int s2 = t2s[t * 4 + 2], s3 = t2s[t * 4 + 3];
  float4 a = *(const float4*)(hbuf2 + (size_t)s0 * HID + c4);
  float4 b = *(const float4*)(hbuf2 + (size_t)s1 * HID + c4);
  float4 c = *(const float4*)(hbuf2 + (size_t)s2 * HID + c4);
  float4 d = *(const float4*)(hbuf2 + (size_t)s3 * HID + c4);
  float4 r;
  r.x = a.x + b.x + c.x + d.x;
  r.y = a.y + b.y + c.y + d.y;
  r.z = a.z + b.z + c.z + d.z;
  r.w = a.w + b.w + c.w + d.w;
  *(float4*)(out + (size_t)t * HID + c4) = r;
}

// ---------------- launch ----------------
extern "C" void kernel_launch(void* const* d_in, const int* in_sizes, int n_in,
                              void* d_out, int out_size, void* d_ws, size_t ws_size,
                              hipStream_t stream){
  const float* x  = (const float*)d_in[0];
  const float* wr = (const float*)d_in[1];
  const float* wg = (const float*)d_in[2];
  const float* wu = (const float*)d_in[3];
  const float* wd = (const float*)d_in[4];
  float* out = (float*)d_out;
  char* ws = (char*)d_ws;

  ushort* xb     = (ushort*)(ws + XB_OFF);
  ushort* hbuf   = (ushort*)(ws + HBUF_OFF);
  float*  topkw  = (float*)(ws + TKW_OFF);
  int*    topki  = (int*)(ws + TKI_OFF);
  int*    rows   = (int*)(ws + ROWS_OFF);
  float*  wts    = (float*)(ws + WTS_OFF);
  int*    offs   = (int*)(ws + OFFS_OFF);
  float*  logits = (float*)(ws + LOGIT_OFF);
  int*    counts = (int*)(ws + CNT_OFF);
  int*    fill   = (int*)(ws + FILL_OFF);
  int*    tlist  = (int*)(ws + TLIST_OFF);
  int*    t2s    = (int*)(ws + T2S_OFF);
  float*  hbuf2  = (float*)(ws + HB2_OFF);

  const bool slotpath = (ws_size >= WS_NEED);

  hipMemsetAsync(ws + ZERO_OFF, 0, ZERO_SZ, stream);

  convert_x_kernel<<<2048, 256, 0, stream>>>(x, xb);
  router_gemm<<<dim3(32, 8), 256, 0, stream>>>(x, wr, logits);
  topk_kernel<<<8, 256, 0, stream>>>(logits, topkw, topki, counts);
  prefix_kernel<<<1, 64, 0, stream>>>(counts, offs, tlist);
  scatter_kernel<<<32, 256, 0, stream>>>(topki, topkw, offs, fill, rows, wts, t2s);
  gateup_kernel<<<dim3(6, MAXT), 512, 0, stream>>>(xb, wg, wu, rows, wts, counts, offs, tlist, hbuf);
  if (slotpath){
    down_kernel<true><<<dim3(8, MAXT), 512, 0, stream>>>(hbuf, wd, rows, counts, offs, tlist, hbuf2);
    combine_kernel<<<dim3(2, T_TOK), 256, 0, stream>>>(hbuf2, t2s, out);
  } else {
    hipMemsetAsync(d_out, 0, (size_t)out_size * sizeof(float), stream);
    down_kernel<false><<<dim3(8, MAXT), 512, 0, stream>>>(hbuf, wd, rows, counts, offs, tlist, out);
  }
}

// Round 7
// 364.973 us; speedup vs baseline: 1.1663x; 1.1663x over previous
//
#include <hip/hip_runtime.h>

#define T_TOK 2048
#define HID   2048
#define INTER 768
#define NE    32
#define NSLOT 8192   // T_TOK * TOP_K
#define MAXT  96     // max (expert, mt) tiles at BM=128

typedef short bf16x8 __attribute__((ext_vector_type(8)));
typedef float f32x4  __attribute__((ext_vector_type(4)));

#if defined(__has_builtin)
#  if __has_builtin(__builtin_amdgcn_global_load_lds)
#    define HAS_GLDS 1
#  endif
#endif
#ifndef HAS_GLDS
#  define HAS_GLDS 0
#endif

__device__ __forceinline__ unsigned short f2b(float f){
  unsigned u = __builtin_bit_cast(unsigned, f);
  u += 0x7fffu + ((u >> 16) & 1u);      // RNE
  return (unsigned short)(u >> 16);
}
__device__ __forceinline__ unsigned pk2(float a, float b){
  return (unsigned)f2b(a) | ((unsigned)f2b(b) << 16);
}

// async 16B global->LDS (no VGPR round trip); sync fallback
__device__ __forceinline__ void stageA16(const ushort* gsrc, ushort* ldst){
#if HAS_GLDS
  __builtin_amdgcn_global_load_lds(
      (const __attribute__((address_space(1))) unsigned int*)gsrc,
      (__attribute__((address_space(3))) unsigned int*)ldst, 16, 0, 0);
#else
  *(uint4*)ldst = *(const uint4*)gsrc;
#endif
}

// ---------------- workspace layout (bytes) ----------------
#define XB_OFF    0ul
#define HBUF_OFF  8388608ul
#define TKW_OFF   20971520ul
#define TKI_OFF   21004288ul
#define ROWS_OFF  21037056ul
#define WTS_OFF   21069824ul
#define OFFS_OFF  21102592ul
#define LOGIT_OFF 21102848ul
#define CNT_OFF   21364992ul
#define FILL_OFF  21365120ul
#define TLIST_OFF 21365248ul
#define T2S_OFF   21365760ul
#define HB2_OFF   21398528ul
#define WS_NEED   (HB2_OFF + 67108864ul)
#define ZERO_OFF  21102848ul
#define ZERO_SZ   (262144ul + 128ul + 128ul)

// ---------------- x fp32 -> bf16 ----------------
__global__ void convert_x_kernel(const float* __restrict__ x, ushort* __restrict__ xb){
  int i = (blockIdx.x * 256 + threadIdx.x) * 8;
  float4 a = *(const float4*)(x + i);
  float4 b = *(const float4*)(x + i + 4);
  uint4 o;
  o.x = pk2(a.x, a.y);
  o.y = pk2(a.z, a.w);
  o.z = pk2(b.x, b.y);
  o.w = pk2(b.z, b.w);
  *(uint4*)(xb + i) = o;
}

// ---------------- router logits (fp32 GEMM, split-K atomic) ----------------
__global__ void router_gemm(const float* __restrict__ x, const float* __restrict__ wr,
                            float* __restrict__ logits){
  const int tt = blockIdx.x;
  const int kb = blockIdx.y;
  __shared__ float xs[64 * 64];
  __shared__ float wsm[64 * 32];
  const int tid = threadIdx.x;
  const int r = tid >> 5, e = tid & 31;
  float acc[8];
#pragma unroll
  for (int i = 0; i < 8; i++) acc[i] = 0.0f;

  for (int sub = 0; sub < 4; ++sub){
    const int k0 = kb * 256 + sub * 64;
    __syncthreads();
#pragma unroll
    for (int j = 0; j < 4; j++){
      int f4 = tid + j * 256;
      int row = f4 >> 4, c4 = f4 & 15;
      float4 v = *(const float4*)(x + (size_t)(tt * 64 + row) * HID + k0 + c4 * 4);
      *(float4*)(xs + row * 64 + c4 * 4) = v;
    }
#pragma unroll
    for (int j = 0; j < 2; j++){
      int f4 = tid + j * 256;
      int row = f4 >> 3, c4 = f4 & 7;
      float4 v = *(const float4*)(wr + (size_t)(k0 + row) * NE + c4 * 4);
      *(float4*)(wsm + row * NE + c4 * 4) = v;
    }
    __syncthreads();
    for (int kk = 0; kk < 64; kk++){
      float wv = wsm[kk * NE + e];
#pragma unroll
      for (int i = 0; i < 8; i++) acc[i] += xs[(r + i * 8) * 64 + kk] * wv;
    }
  }
#pragma unroll
  for (int i = 0; i < 8; i++)
    atomicAdd(&logits[(size_t)(tt * 64 + r + i * 8) * NE + e], acc[i]);
}

// ---------------- softmax + top-4 + renorm + counts ----------------
__global__ void topk_kernel(const float* __restrict__ logits, float* __restrict__ topk_w,
                            int* __restrict__ topk_i, int* __restrict__ counts){
  int t = blockIdx.x * blockDim.x + threadIdx.x;
  if (t >= T_TOK) return;
  float l[32];
  const float4* lp = (const float4*)(logits + (size_t)t * NE);
#pragma unroll
  for (int i = 0; i < 8; i++){
    float4 v = lp[i];
    l[i*4+0] = v.x; l[i*4+1] = v.y; l[i*4+2] = v.z; l[i*4+3] = v.w;
  }
  float m = l[0];
#pragma unroll
  for (int i = 1; i < 32; i++) m = fmaxf(m, l[i]);
#pragma unroll
  for (int i = 0; i < 32; i++) l[i] = __expf(l[i] - m);
  float wsel[4]; int isel[4];
#pragma unroll
  for (int k = 0; k < 4; k++){
    float best = l[0]; int bi = 0;
#pragma unroll
    for (int i = 1; i < 32; i++){ if (l[i] > best){ best = l[i]; bi = i; } }
    wsel[k] = best; isel[k] = bi; l[bi] = -1.0f;
  }
  float s4 = wsel[0] + wsel[1] + wsel[2] + wsel[3];
  float inv = 1.0f / s4;
#pragma unroll
  for (int k = 0; k < 4; k++){
    topk_w[t * 4 + k] = wsel[k] * inv;
    topk_i[t * 4 + k] = isel[k];
    atomicAdd(&counts[isel[k]], 1);
  }
}

__global__ void prefix_kernel(const int* __restrict__ counts, int* __restrict__ offsets,
                              int* __restrict__ tlist){
  if (threadIdx.x == 0){
    int a = 0; offsets[0] = 0; int nt_ = 0;
    for (int e = 0; e < NE; e++){
      int c = counts[e];
      for (int m = 0; m * 128 < c && nt_ < MAXT; m++) tlist[nt_++] = e | (m << 16);
      a += c; offsets[e + 1] = a;
    }
    for (; nt_ < MAXT; nt_++) tlist[nt_] = -1;
  }
}

__global__ void scatter_kernel(const int* __restrict__ topk_i, const float* __restrict__ topk_w,
                               const int* __restrict__ offsets, int* __restrict__ fill,
                               int* __restrict__ rows, float* __restrict__ wts,
                               int* __restrict__ t2s){
  int gid = blockIdx.x * 256 + threadIdx.x;
  int t = gid >> 2;
  int e = topk_i[gid];
  int pos = atomicAdd(&fill[e], 1);
  int s = offsets[e] + pos;
  rows[s] = t;
  wts[s] = topk_w[gid];
  t2s[gid] = s;
}

// ---------------- gate+up GEMM ----------------
// BM=128, BN=64 (x2 matrices), BK=32, 64 K-steps, 512 threads (8 waves,
// 4m x 2n). LDS 32 KB (2 x 16 KB double buffer) + VGPR cap 85 via
// __launch_bounds__(512,6) -> 3 blocks/CU = 768 slots ~= active block count
// (round-6 lesson: 2 blocks/CU = 512 slots forced a 1.5-round schedule,
// avg occ 37%, BW 2.6 TB/s). A staged by global_load_lds (16B, lane-linear
// dest, swizzle applied on the GLOBAL source per m173); B fp32->bf16 via
// regs. Chunk-XOR ko^((row>>1)&3) gives exactly-2-way (free) b128 reads.
#define NT_GU 64
#define GU_BUF 8192   // ushorts per buffer: A 4096 + Bg 2048 + Bu 2048
__global__ __launch_bounds__(512, 6) void gateup_kernel(
    const ushort* __restrict__ xb, const float* __restrict__ wg,
    const float* __restrict__ wu, const int* __restrict__ rows,
    const float* __restrict__ wts, const int* __restrict__ counts,
    const int* __restrict__ offsets, const int* __restrict__ tlist,
    ushort* __restrict__ hbuf)
{
  const int w = tlist[blockIdx.y];
  if (w < 0) return;
  const int e = w & 0xffff, mt = w >> 16;
  const int nt = blockIdx.x;          // 0..11
  const int cnt = counts[e];
  const int off = offsets[e];
  const int n0 = nt * 64;

  __shared__ __align__(16) ushort lds[2 * GU_BUF];  // 32 KB

  const int tid = threadIdx.x;

  // A staging: thread -> (row ar, dest chunk adc); logical chunk pre-swizzled
  const int ar = tid >> 2, adc = tid & 3;
  const int alc = adc ^ ((ar >> 1) & 3);
  const int srow = mt * 128 + ar;
  const int tokA = rows[off + (srow < cnt ? srow : 0)];
  const ushort* agp = xb + (size_t)tokA * HID + alc * 8;

  // B staging: thread owns one col (bn), 4 k's (kg)
  const int bn = tid & 63, kg = tid >> 6;
  const size_t wofs = (size_t)e * (HID * INTER) + (size_t)(kg * 4) * INTER + n0 + bn;
  const float* wgp = wg + wofs;
  const float* wup = wu + wofs;
  const int bofs = bn * 32 + ((kg >> 1) ^ ((bn >> 1) & 3)) * 8 + (kg & 1) * 4;

  // compute roles: 4m x 2n waves
  const int lane = tid & 63, wv = tid >> 6;
  const int wm = wv >> 1, wn = wv & 1;
  const int fr = lane & 15, ko = lane >> 4;

  int aoff[2], boff[2];
#pragma unroll
  for (int mf = 0; mf < 2; mf++){
    int r = wm * 32 + mf * 16 + fr;
    aoff[mf] = r * 32 + ((ko ^ ((r >> 1) & 3)) * 8);
  }
#pragma unroll
  for (int nf = 0; nf < 2; nf++){
    int c = wn * 32 + nf * 16 + fr;
    boff[nf] = c * 32 + ((ko ^ ((c >> 1) & 3)) * 8);
  }

  f32x4 accg[2][2], accu[2][2];
#pragma unroll
  for (int i = 0; i < 2; i++)
#pragma unroll
    for (int j = 0; j < 2; j++){ accg[i][j] = (f32x4)(0.0f); accu[i][j] = (f32x4)(0.0f); }

  float sg[4], su[4];

  auto loadB = [&](int k0){
    const float* pg_ = wgp + (size_t)k0 * INTER;
    const float* pu_ = wup + (size_t)k0 * INTER;
#pragma unroll
    for (int kk = 0; kk < 4; kk++){ sg[kk] = pg_[(size_t)kk * INTER]; su[kk] = pu_[(size_t)kk * INTER]; }
  };
  auto writeB = [&](int base){
    uint2 pg, pu;
    pg.x = pk2(sg[0], sg[1]); pg.y = pk2(sg[2], sg[3]);
    pu.x = pk2(su[0], su[1]); pu.y = pk2(su[2], su[3]);
    *(uint2*)(lds + base + 4096 + bofs) = pg;
    *(uint2*)(lds + base + 6144 + bofs) = pu;
  };
  auto computeTile = [&](int base){
    bf16x8 a[2], bg2[2], bu2[2];
#pragma unroll
    for (int mf = 0; mf < 2; mf++) a[mf] = *(const bf16x8*)(lds + base + aoff[mf]);
#pragma unroll
    for (int nf = 0; nf < 2; nf++){
      bg2[nf] = *(const bf16x8*)(lds + base + 4096 + boff[nf]);
      bu2[nf] = *(const bf16x8*)(lds + base + 6144 + boff[nf]);
    }
#pragma unroll
    for (int mf = 0; mf < 2; mf++)
#pragma unroll
      for (int nf = 0; nf < 2; nf++){
        accg[mf][nf] = __builtin_amdgcn_mfma_f32_16x16x32_bf16(a[mf], bg2[nf], accg[mf][nf], 0, 0, 0);
        accu[mf][nf] = __builtin_amdgcn_mfma_f32_16x16x32_bf16(a[mf], bu2[nf], accu[mf][nf], 0, 0, 0);
      }
  };

  // prologue
  stageA16(agp, lds + tid * 8);
  loadB(0);
  writeB(0);
  __syncthreads();

  int cb = 0;
  for (int t = 0; t < NT_GU; ++t){
    const int nb = cb ^ GU_BUF;
    if (t + 1 < NT_GU){
      stageA16(agp + (t + 1) * 32, lds + nb + tid * 8);
      loadB((t + 1) * 32);
    }
    computeTile(cb);
    if (t + 1 < NT_GU) writeB(nb);
    __syncthreads();
    cb = nb;
  }

  // epilogue
#pragma unroll
  for (int mf = 0; mf < 2; mf++)
#pragma unroll
    for (int j = 0; j < 4; j++){
      int rl = wm * 32 + mf * 16 + ko * 4 + j;
      int gr = mt * 128 + rl;
      if (gr < cnt){
        float w2 = wts[off + gr];
        size_t robase = (size_t)(off + gr) * INTER + n0;
#pragma unroll
        for (int nf = 0; nf < 2; nf++){
          float g = accg[mf][nf][j], u = accu[mf][nf][j];
          float h = (g / (1.0f + __expf(-g))) * u * w2;
          hbuf[robase + wn * 32 + nf * 16 + fr] = f2b(h);
        }
      }
    }
}

// ---------------- down GEMM: BM=128, BN=64, BK=32, 24 K-steps ----------------
#define NT_DN 24
#define DN_BUF 6144   // ushorts per buffer: A 4096 + B 2048
template<bool SLOT>
__global__ __launch_bounds__(512, 6) void down_kernel(
    const ushort* __restrict__ hbuf, const float* __restrict__ wd,
    const int* __restrict__ rows, const int* __restrict__ counts,
    const int* __restrict__ offsets, const int* __restrict__ tlist,
    float* __restrict__ outp)
{
  const int w = tlist[blockIdx.y];
  if (w < 0) return;
  const int e = w & 0xffff, mt = w >> 16;
  const int nt = blockIdx.x;          // 0..31
  const int cnt = counts[e];
  const int off = offsets[e];
  const int n0 = nt * 64;

  __shared__ __align__(16) ushort lds[2 * DN_BUF];  // 24 KB

  const int tid = threadIdx.x;

  const int ar = tid >> 2, adc = tid & 3;
  const int alc = adc ^ ((ar >> 1) & 3);
  const int srow = mt * 128 + ar;
  const int slotA = off + (srow < cnt ? srow : 0);
  const ushort* agp = hbuf + (size_t)slotA * INTER + alc * 8;

  const int bn = tid & 63, kg = tid >> 6;
  const float* wdp = wd + (size_t)e * (INTER * HID) + (size_t)(kg * 4) * HID + n0 + bn;
  const int bofs = bn * 32 + ((kg >> 1) ^ ((bn >> 1) & 3)) * 8 + (kg & 1) * 4;

  const int lane = tid & 63, wv = tid >> 6;
  const int wm = wv >> 1, wn = wv & 1;
  const int fr = lane & 15, ko = lane >> 4;

  int aoff[2], boff[2];
#pragma unroll
  for (int mf = 0; mf < 2; mf++){
    int r = wm * 32 + mf * 16 + fr;
    aoff[mf] = r * 32 + ((ko ^ ((r >> 1) & 3)) * 8);
  }
#pragma unroll
  for (int nf = 0; nf < 2; nf++){
    int c = wn * 32 + nf * 16 + fr;
    boff[nf] = c * 32 + ((ko ^ ((c >> 1) & 3)) * 8);
  }

  f32x4 acc[2][2];
#pragma unroll
  for (int i = 0; i < 2; i++)
#pragma unroll
    for (int j = 0; j < 2; j++) acc[i][j] = (f32x4)(0.0f);

  float sb[4];

  auto loadB = [&](int k0){
    const float* p = wdp + (size_t)k0 * HID;
#pragma unroll
    for (int kk = 0; kk < 4; kk++) sb[kk] = p[(size_t)kk * HID];
  };
  auto writeB = [&](int base){
    uint2 pb;
    pb.x = pk2(sb[0], sb[1]); pb.y = pk2(sb[2], sb[3]);
    *(uint2*)(lds + base + 4096 + bofs) = pb;
  };
  auto computeTile = [&](int base){
    bf16x8 a[2], b2[2];
#pragma unroll
    for (int mf = 0; mf < 2; mf++) a[mf] = *(const bf16x8*)(lds + base + aoff[mf]);
#pragma unroll
    for (int nf = 0; nf < 2; nf++) b2[nf] = *(const bf16x8*)(lds + base + 4096 + boff[nf]);
#pragma unroll
    for (int mf = 0; mf < 2; mf++)
#pragma unroll
      for (int nf = 0; nf < 2; nf++)
        acc[mf][nf] = __builtin_amdgcn_mfma_f32_16x16x32_bf16(a[mf], b2[nf], acc[mf][nf], 0, 0, 0);
  };

  stageA16(agp, lds + tid * 8);
  loadB(0);
  writeB(0);
  __syncthreads();

  int cb = 0;
  for (int t = 0; t < NT_DN; ++t){
    const int nb = cb ^ DN_BUF;
    if (t + 1 < NT_DN){
      stageA16(agp + (t + 1) * 32, lds + nb + tid * 8);
      loadB((t + 1) * 32);
    }
    computeTile(cb);
    if (t + 1 < NT_DN) writeB(nb);
    __syncthreads();
    cb = nb;
  }

#pragma unroll
  for (int mf = 0; mf < 2; mf++)
#pragma unroll
    for (int j = 0; j < 4; j++){
      int rl = wm * 32 + mf * 16 + ko * 4 + j;
      int gr = mt * 128 + rl;
      if (gr < cnt){
        if (SLOT){
          float* obase = outp + (size_t)(off + gr) * HID + n0;
#pragma unroll
          for (int nf = 0; nf < 2; nf++)
            obase[wn * 32 + nf * 16 + fr] = acc[mf][nf][j];
        } else {
          int tok = rows[off + gr];
          float* obase = outp + (size_t)tok * HID + n0;
#pragma unroll
          for (int nf = 0; nf < 2; nf++)
            atomicAdd(obase + wn * 32 + nf * 16 + fr, acc[mf][nf][j]);
        }
      }
    }
}

// ---------------- combine: out[t] = sum of token t's 4 slot rows ----------------
__global__ void combine_kernel(const float* __restrict__ hbuf2, const int* __restrict__ t2s,
                               float* __restrict__ out){
  const int t = blockIdx.y;
  const int c4 = (blockIdx.x * 256 + threadIdx.x) * 4;
  const int s0 = t2s[t * 4 + 0], s1 = t2s[t * 4 + 1];
  const int s2 = t2s[t * 4 + 2], s3 = t2s[t * 4 + 3];
  float4 a = *(const float4*)(hbuf2 + (size_t)s0 * HID + c4);
  float4 b = *(const float4*)(hbuf2 + (size_t)s1 * HID + c4);
  float4 c = *(const float4*)(hbuf2 + (size_t)s2 * HID + c4);
  float4 d = *(const float4*)(hbuf2 + (size_t)s3 * HID + c4);
  float4 r;
  r.x = a.x + b.x + c.x + d.x;
  r.y = a.y + b.y + c.y + d.y;
  r.z = a.z + b.z + c.z + d.z;
  r.w = a.w + b.w + c.w + d.w;
  *(float4*)(out + (size_t)t * HID + c4) = r;
}

// ---------------- launch ----------------
extern "C" void kernel_launch(void* const* d_in, const int* in_sizes, int n_in,
                              void* d_out, int out_size, void* d_ws, size_t ws_size,
                              hipStream_t stream){
  const float* x  = (const float*)d_in[0];
  const float* wr = (const float*)d_in[1];
  const float* wg = (const float*)d_in[2];
  const float* wu = (const float*)d_in[3];
  const float* wd = (const float*)d_in[4];
  float* out = (float*)d_out;
  char* ws = (char*)d_ws;

  ushort* xb     = (ushort*)(ws + XB_OFF);
  ushort* hbuf   = (ushort*)(ws + HBUF_OFF);
  float*  topkw  = (float*)(ws + TKW_OFF);
  int*    topki  = (int*)(ws + TKI_OFF);
  int*    rows   = (int*)(ws + ROWS_OFF);
  float*  wts    = (float*)(ws + WTS_OFF);
  int*    offs   = (int*)(ws + OFFS_OFF);
  float*  logits = (float*)(ws + LOGIT_OFF);
  int*    counts = (int*)(ws + CNT_OFF);
  int*    fill   = (int*)(ws + FILL_OFF);
  int*    tlist  = (int*)(ws + TLIST_OFF);
  int*    t2s    = (int*)(ws + T2S_OFF);
  float*  hbuf2  = (float*)(ws + HB2_OFF);

  const bool slotpath = (ws_size >= WS_NEED);

  hipMemsetAsync(ws + ZERO_OFF, 0, ZERO_SZ, stream);

  convert_x_kernel<<<2048, 256, 0, stream>>>(x, xb);
  router_gemm<<<dim3(32, 8), 256, 0, stream>>>(x, wr, logits);
  topk_kernel<<<8, 256, 0, stream>>>(logits, topkw, topki, counts);
  prefix_kernel<<<1, 64, 0, stream>>>(counts, offs, tlist);
  scatter_kernel<<<32, 256, 0, stream>>>(topki, topkw, offs, fill, rows, wts, t2s);
  gateup_kernel<<<dim3(12, MAXT), 512, 0, stream>>>(xb, wg, wu, rows, wts, counts, offs, tlist, hbuf);
  if (slotpath){
    down_kernel<true><<<dim3(32, MAXT), 512, 0, stream>>>(hbuf, wd, rows, counts, offs, tlist, hbuf2);
    combine_kernel<<<dim3(2, T_TOK), 256, 0, stream>>>(hbuf2, t2s, out);
  } else {
    hipMemsetAsync(d_out, 0, (size_t)out_size * sizeof(float), stream);
    down_kernel<false><<<dim3(32, MAXT), 512, 0, stream>>>(hbuf, wd, rows, counts, offs, tlist, out);
  }
}

// Round 8
// 356.311 us; speedup vs baseline: 1.1946x; 1.0243x over previous
//
#include <hip/hip_runtime.h>

#define T_TOK 2048
#define HID   2048
#define INTER 768
#define NE    32
#define NSLOT 8192   // T_TOK * TOP_K
#define MAXT  96     // max (expert, mt) tiles at BM=128

typedef short bf16x8 __attribute__((ext_vector_type(8)));
typedef float f32x4  __attribute__((ext_vector_type(4)));

#if defined(__has_builtin)
#  if __has_builtin(__builtin_amdgcn_global_load_lds)
#    define HAS_GLDS 1
#  endif
#endif
#ifndef HAS_GLDS
#  define HAS_GLDS 0
#endif

__device__ __forceinline__ unsigned short f2b(float f){
  unsigned u = __builtin_bit_cast(unsigned, f);
  u += 0x7fffu + ((u >> 16) & 1u);      // RNE
  return (unsigned short)(u >> 16);
}
__device__ __forceinline__ unsigned pk2(float a, float b){
  return (unsigned)f2b(a) | ((unsigned)f2b(b) << 16);
}
__device__ __forceinline__ float b2f(unsigned short u){
  unsigned x = ((unsigned)u) << 16;
  return __builtin_bit_cast(float, x);
}

__device__ __forceinline__ void stageA16(const ushort* gsrc, ushort* ldst){
#if HAS_GLDS
  __builtin_amdgcn_global_load_lds(
      (const __attribute__((address_space(1))) unsigned int*)gsrc,
      (__attribute__((address_space(3))) unsigned int*)ldst, 16, 0, 0);
#else
  *(uint4*)ldst = *(const uint4*)gsrc;
#endif
}

// ---------------- workspace layout (bytes) ----------------
#define XB_OFF    0ul           // bf16 x  [2048][2048]  = 8388608
#define GBUF_OFF  8388608ul     // bf16 g, then h in-place [8192][768] = 12582912
#define TKW_OFF   20971520ul    // f32 topk_w [2048][4]
#define TKI_OFF   21004288ul
#define ROWS_OFF  21037056ul
#define WTS_OFF   21069824ul
#define OFFS_OFF  21102592ul
#define LOGIT_OFF 21102848ul    // zeroed
#define CNT_OFF   21364992ul    // zeroed
#define FILL_OFF  21365120ul    // zeroed
#define TLIST_OFF 21365248ul
#define UBUF_OFF  21365760ul    // bf16 u [8192][768] = 12582912 (ends ~34 MB)
#define ZERO_OFF  21102848ul
#define ZERO_SZ   (262144ul + 128ul + 128ul)

// ---------------- x fp32 -> bf16 ----------------
__global__ void convert_x_kernel(const float* __restrict__ x, ushort* __restrict__ xb){
  int i = (blockIdx.x * 256 + threadIdx.x) * 8;
  float4 a = *(const float4*)(x + i);
  float4 b = *(const float4*)(x + i + 4);
  uint4 o;
  o.x = pk2(a.x, a.y);
  o.y = pk2(a.z, a.w);
  o.z = pk2(b.x, b.y);
  o.w = pk2(b.z, b.w);
  *(uint4*)(xb + i) = o;
}

// ---------------- router logits (fp32 GEMM, split-K atomic) ----------------
__global__ void router_gemm(const float* __restrict__ x, const float* __restrict__ wr,
                            float* __restrict__ logits){
  const int tt = blockIdx.x;
  const int kb = blockIdx.y;
  __shared__ float xs[64 * 64];
  __shared__ float wsm[64 * 32];
  const int tid = threadIdx.x;
  const int r = tid >> 5, e = tid & 31;
  float acc[8];
#pragma unroll
  for (int i = 0; i < 8; i++) acc[i] = 0.0f;

  for (int sub = 0; sub < 4; ++sub){
    const int k0 = kb * 256 + sub * 64;
    __syncthreads();
#pragma unroll
    for (int j = 0; j < 4; j++){
      int f4 = tid + j * 256;
      int row = f4 >> 4, c4 = f4 & 15;
      float4 v = *(const float4*)(x + (size_t)(tt * 64 + row) * HID + k0 + c4 * 4);
      *(float4*)(xs + row * 64 + c4 * 4) = v;
    }
#pragma unroll
    for (int j = 0; j < 2; j++){
      int f4 = tid + j * 256;
      int row = f4 >> 3, c4 = f4 & 7;
      float4 v = *(const float4*)(wr + (size_t)(k0 + row) * NE + c4 * 4);
      *(float4*)(wsm + row * NE + c4 * 4) = v;
    }
    __syncthreads();
    for (int kk = 0; kk < 64; kk++){
      float wv = wsm[kk * NE + e];
#pragma unroll
      for (int i = 0; i < 8; i++) acc[i] += xs[(r + i * 8) * 64 + kk] * wv;
    }
  }
#pragma unroll
  for (int i = 0; i < 8; i++)
    atomicAdd(&logits[(size_t)(tt * 64 + r + i * 8) * NE + e], acc[i]);
}

// ---------------- softmax + top-4 + renorm + counts ----------------
__global__ void topk_kernel(const float* __restrict__ logits, float* __restrict__ topk_w,
                            int* __restrict__ topk_i, int* __restrict__ counts){
  int t = blockIdx.x * blockDim.x + threadIdx.x;
  if (t >= T_TOK) return;
  float l[32];
  const float4* lp = (const float4*)(logits + (size_t)t * NE);
#pragma unroll
  for (int i = 0; i < 8; i++){
    float4 v = lp[i];
    l[i*4+0] = v.x; l[i*4+1] = v.y; l[i*4+2] = v.z; l[i*4+3] = v.w;
  }
  float m = l[0];
#pragma unroll
  for (int i = 1; i < 32; i++) m = fmaxf(m, l[i]);
#pragma unroll
  for (int i = 0; i < 32; i++) l[i] = __expf(l[i] - m);
  float wsel[4]; int isel[4];
#pragma unroll
  for (int k = 0; k < 4; k++){
    float best = l[0]; int bi = 0;
#pragma unroll
    for (int i = 1; i < 32; i++){ if (l[i] > best){ best = l[i]; bi = i; } }
    wsel[k] = best; isel[k] = bi; l[bi] = -1.0f;
  }
  float s4 = wsel[0] + wsel[1] + wsel[2] + wsel[3];
  float inv = 1.0f / s4;
#pragma unroll
  for (int k = 0; k < 4; k++){
    topk_w[t * 4 + k] = wsel[k] * inv;
    topk_i[t * 4 + k] = isel[k];
    atomicAdd(&counts[isel[k]], 1);
  }
}

__global__ void prefix_kernel(const int* __restrict__ counts, int* __restrict__ offsets,
                              int* __restrict__ tlist){
  if (threadIdx.x == 0){
    int a = 0; offsets[0] = 0; int nt_ = 0;
    for (int e = 0; e < NE; e++){
      int c = counts[e];
      for (int m = 0; m * 128 < c && nt_ < MAXT; m++) tlist[nt_++] = e | (m << 16);
      a += c; offsets[e + 1] = a;
    }
    for (; nt_ < MAXT; nt_++) tlist[nt_] = -1;
  }
}

__global__ void scatter_kernel(const int* __restrict__ topk_i, const float* __restrict__ topk_w,
                               const int* __restrict__ offsets, int* __restrict__ fill,
                               int* __restrict__ rows, float* __restrict__ wts){
  int gid = blockIdx.x * 256 + threadIdx.x;
  int t = gid >> 2;
  int e = topk_i[gid];
  int pos = atomicAdd(&fill[e], 1);
  int s = offsets[e] + pos;
  rows[s] = t;
  wts[s] = topk_w[gid];
}

// ---------------- gate/up GEMM (split matrices) ----------------
// BM=128, BN=256, BK=32, 512 thr (8 waves, 2m x 4n, 16 MFMA/step/wave).
// B loads: wave owns 4 consecutive k-rows; each instr = 256 consecutive
// floats = 1 KB (m13 streaming pattern). Thread register-transposes its
// 4x4 block and writes packed b64 into XOR-swizzled [col][k] LDS
// (even-XOR on 4-ushort chunks keeps b128 reads k-ordered).
// A via global_load_lds, chunk-XOR applied on the GLOBAL source (m173).
// LDS padded to 57344 B -> exactly 2 blocks/CU, VGPR cap 128 (r4/r5 lesson).
#define NT_GU 64
#define LDS_STRIDE 12288   // ushorts: A 4096 | B 8192
__global__ __launch_bounds__(512) void guv_kernel(
    const ushort* __restrict__ xb, const float* __restrict__ wg,
    const float* __restrict__ wu, const int* __restrict__ rows,
    const int* __restrict__ counts, const int* __restrict__ offsets,
    const int* __restrict__ tlist, ushort* __restrict__ gbuf,
    ushort* __restrict__ ubuf)
{
  const int w = tlist[blockIdx.y];
  if (w < 0) return;
  const int e = w & 0xffff, mt = w >> 16;
  const int mat = blockIdx.x & 1, nt = blockIdx.x >> 1;   // nt 0..2
  const int cnt = counts[e], off = offsets[e];
  const int n0 = nt * 256;

  __shared__ __align__(16) ushort lds[2 * LDS_STRIDE + 4096];  // 57344 B

  const int tid = threadIdx.x;
  const int lane = tid & 63, wv = tid >> 6;

  // A staging: row ar, stored chunk sc=tid&3 holds logical chunk sc^(ar&3)
  const int ar = tid >> 2;
  const int aq = (tid & 3) ^ (ar & 3);
  const int srow = mt * 128 + ar;
  const int tokA = rows[off + (srow < cnt ? srow : 0)];
  const ushort* agp = xb + (size_t)tokA * HID + aq * 8;

  // B staging: wave wv -> rows 4wv..4wv+3 per step; lane -> cols 4*lane..+3
  const float* wsel = mat ? wu : wg;
  const float* bgp = wsel + (size_t)e * (HID * INTER) + (size_t)(wv * 4) * INTER + n0 + lane * 4;
  const int bwbase = lane * 128 + ((wv ^ ((lane & 3) << 1)) << 2);

  // compute roles
  const int wm = wv >> 2, wn = wv & 3;
  const int fr = lane & 15, ko = lane >> 4;
  int aoff[4], boff[4];
#pragma unroll
  for (int mf = 0; mf < 4; mf++){
    int r = wm * 64 + mf * 16 + fr;
    aoff[mf] = r * 32 + ((ko ^ (r & 3)) << 3);
  }
#pragma unroll
  for (int nf = 0; nf < 4; nf++){
    int c = wn * 64 + nf * 16 + fr;
    boff[nf] = c * 32 + (((ko * 2) ^ (((c >> 2) & 3) << 1)) << 2);
  }

  f32x4 acc[4][4];
#pragma unroll
  for (int i = 0; i < 4; i++)
#pragma unroll
    for (int j = 0; j < 4; j++) acc[i][j] = (f32x4)(0.0f);

  float4 br0, br1, br2, br3;

  auto loadB = [&](int k0){
    br0 = *(const float4*)(bgp + (size_t)(k0 + 0) * INTER);
    br1 = *(const float4*)(bgp + (size_t)(k0 + 1) * INTER);
    br2 = *(const float4*)(bgp + (size_t)(k0 + 2) * INTER);
    br3 = *(const float4*)(bgp + (size_t)(k0 + 3) * INTER);
  };
  auto writeB = [&](int cb){
    ushort* bd = lds + cb + 4096;
#pragma unroll
    for (int i = 0; i < 4; i++){
      uint2 p;
      p.x = pk2((&br0.x)[i], (&br1.x)[i]);
      p.y = pk2((&br2.x)[i], (&br3.x)[i]);
      *(uint2*)(bd + bwbase + i * 32) = p;
    }
  };
  auto compute = [&](int cb){
    const ushort* A = lds + cb;
    const ushort* B = lds + cb + 4096;
    bf16x8 a[4], b[4];
#pragma unroll
    for (int mf = 0; mf < 4; mf++) a[mf] = *(const bf16x8*)(A + aoff[mf]);
#pragma unroll
    for (int nf = 0; nf < 4; nf++) b[nf] = *(const bf16x8*)(B + boff[nf]);
#pragma unroll
    for (int mf = 0; mf < 4; mf++)
#pragma unroll
      for (int nf = 0; nf < 4; nf++)
        acc[mf][nf] = __builtin_amdgcn_mfma_f32_16x16x32_bf16(a[mf], b[nf], acc[mf][nf], 0, 0, 0);
  };

  // prologue
  stageA16(agp, lds + tid * 8);
  loadB(0);
  writeB(0);
  __syncthreads();

  int cb = 0;
  for (int t = 0; t < NT_GU; ++t){
    const int nb = cb ^ LDS_STRIDE;
    if (t + 1 < NT_GU){
      stageA16(agp + (t + 1) * 32, lds + nb + tid * 8);
      loadB((t + 1) * 32);
    }
    compute(cb);
    if (t + 1 < NT_GU) writeB(nb);
    __syncthreads();
    cb = nb;
  }

  // epilogue: raw GEMM result, bf16
  ushort* obuf = mat ? ubuf : gbuf;
#pragma unroll
  for (int mf = 0; mf < 4; mf++)
#pragma unroll
    for (int j = 0; j < 4; j++){
      int rl = wm * 64 + mf * 16 + ko * 4 + j;
      int gr = mt * 128 + rl;
      if (gr < cnt){
        size_t rb = (size_t)(off + gr) * INTER + n0;
#pragma unroll
        for (int nf = 0; nf < 4; nf++)
          obuf[rb + wn * 64 + nf * 16 + fr] = f2b(acc[mf][nf][j]);
      }
    }
}

// ---------------- fuse: h = silu(g) * u * wt  (in place over gbuf) ----------------
__global__ void fuse_kernel(ushort* __restrict__ gbuf, const ushort* __restrict__ ubuf,
                            const float* __restrict__ wts){
  const int s = blockIdx.x;
  const int c = threadIdx.x * 4;   // 192 threads cover 768
  const float wt = wts[s];
  size_t base = (size_t)s * INTER + c;
  uint2 gv = *(const uint2*)(gbuf + base);
  uint2 uv = *(const uint2*)(ubuf + base);
  float h[4];
  {
    float g0 = b2f((unsigned short)gv.x),        u0 = b2f((unsigned short)uv.x);
    float g1 = b2f((unsigned short)(gv.x >> 16)), u1 = b2f((unsigned short)(uv.x >> 16));
    float g2 = b2f((unsigned short)gv.y),        u2 = b2f((unsigned short)uv.y);
    float g3 = b2f((unsigned short)(gv.y >> 16)), u3 = b2f((unsigned short)(uv.y >> 16));
    h[0] = (g0 / (1.0f + __expf(-g0))) * u0 * wt;
    h[1] = (g1 / (1.0f + __expf(-g1))) * u1 * wt;
    h[2] = (g2 / (1.0f + __expf(-g2))) * u2 * wt;
    h[3] = (g3 / (1.0f + __expf(-g3))) * u3 * wt;
  }
  uint2 o; o.x = pk2(h[0], h[1]); o.y = pk2(h[2], h[3]);
  *(uint2*)(gbuf + base) = o;
}

// ---------------- down GEMM: out[tok] += h @ wd (atomic) ----------------
// Same template: BM=128, BN=256, BK=32, 24 K-steps, nt=8.
#define NT_DN 24
__global__ __launch_bounds__(512) void down_kernel(
    const ushort* __restrict__ hbuf, const float* __restrict__ wd,
    const int* __restrict__ rows, const int* __restrict__ counts,
    const int* __restrict__ offsets, const int* __restrict__ tlist,
    float* __restrict__ out)
{
  const int w = tlist[blockIdx.y];
  if (w < 0) return;
  const int e = w & 0xffff, mt = w >> 16;
  const int nt = blockIdx.x;   // 0..7
  const int cnt = counts[e], off = offsets[e];
  const int n0 = nt * 256;

  __shared__ __align__(16) ushort lds[2 * LDS_STRIDE + 4096];  // 57344 B

  const int tid = threadIdx.x;
  const int lane = tid & 63, wv = tid >> 6;

  const int ar = tid >> 2;
  const int aq = (tid & 3) ^ (ar & 3);
  const int srow = mt * 128 + ar;
  const int slotA = off + (srow < cnt ? srow : 0);
  const ushort* agp = hbuf + (size_t)slotA * INTER + aq * 8;

  const float* bgp = wd + (size_t)e * (INTER * HID) + (size_t)(wv * 4) * HID + n0 + lane * 4;
  const int bwbase = lane * 128 + ((wv ^ ((lane & 3) << 1)) << 2);

  const int wm = wv >> 2, wn = wv & 3;
  const int fr = lane & 15, ko = lane >> 4;
  int aoff[4], boff[4];
#pragma unroll
  for (int mf = 0; mf < 4; mf++){
    int r = wm * 64 + mf * 16 + fr;
    aoff[mf] = r * 32 + ((ko ^ (r & 3)) << 3);
  }
#pragma unroll
  for (int nf = 0; nf < 4; nf++){
    int c = wn * 64 + nf * 16 + fr;
    boff[nf] = c * 32 + (((ko * 2) ^ (((c >> 2) & 3) << 1)) << 2);
  }

  f32x4 acc[4][4];
#pragma unroll
  for (int i = 0; i < 4; i++)
#pragma unroll
    for (int j = 0; j < 4; j++) acc[i][j] = (f32x4)(0.0f);

  float4 br0, br1, br2, br3;

  auto loadB = [&](int k0){
    br0 = *(const float4*)(bgp + (size_t)(k0 + 0) * HID);
    br1 = *(const float4*)(bgp + (size_t)(k0 + 1) * HID);
    br2 = *(const float4*)(bgp + (size_t)(k0 + 2) * HID);
    br3 = *(const float4*)(bgp + (size_t)(k0 + 3) * HID);
  };
  auto writeB = [&](int cb){
    ushort* bd = lds + cb + 4096;
#pragma unroll
    for (int i = 0; i < 4; i++){
      uint2 p;
      p.x = pk2((&br0.x)[i], (&br1.x)[i]);
      p.y = pk2((&br2.x)[i], (&br3.x)[i]);
      *(uint2*)(bd + bwbase + i * 32) = p;
    }
  };
  auto compute = [&](int cb){
    const ushort* A = lds + cb;
    const ushort* B = lds + cb + 4096;
    bf16x8 a[4], b[4];
#pragma unroll
    for (int mf = 0; mf < 4; mf++) a[mf] = *(const bf16x8*)(A + aoff[mf]);
#pragma unroll
    for (int nf = 0; nf < 4; nf++) b[nf] = *(const bf16x8*)(B + boff[nf]);
#pragma unroll
    for (int mf = 0; mf < 4; mf++)
#pragma unroll
      for (int nf = 0; nf < 4; nf++)
        acc[mf][nf] = __builtin_amdgcn_mfma_f32_16x16x32_bf16(a[mf], b[nf], acc[mf][nf], 0, 0, 0);
  };

  stageA16(agp, lds + tid * 8);
  loadB(0);
  writeB(0);
  __syncthreads();

  int cb = 0;
  for (int t = 0; t < NT_DN; ++t){
    const int nb = cb ^ LDS_STRIDE;
    if (t + 1 < NT_DN){
      stageA16(agp + (t + 1) * 32, lds + nb + tid * 8);
      loadB((t + 1) * 32);
    }
    compute(cb);
    if (t + 1 < NT_DN) writeB(nb);
    __syncthreads();
    cb = nb;
  }

#pragma unroll
  for (int mf = 0; mf < 4; mf++)
#pragma unroll
    for (int j = 0; j < 4; j++){
      int rl = wm * 64 + mf * 16 + ko * 4 + j;
      int gr = mt * 128 + rl;
      if (gr < cnt){
        int tok = rows[off + gr];
        float* obase = out + (size_t)tok * HID + n0;
#pragma unroll
        for (int nf = 0; nf < 4; nf++)
          atomicAdd(obase + wn * 64 + nf * 16 + fr, acc[mf][nf][j]);
      }
    }
}

// ---------------- launch ----------------
extern "C" void kernel_launch(void* const* d_in, const int* in_sizes, int n_in,
                              void* d_out, int out_size, void* d_ws, size_t ws_size,
                              hipStream_t stream){
  const float* x  = (const float*)d_in[0];
  const float* wr = (const float*)d_in[1];
  const float* wg = (const float*)d_in[2];
  const float* wu = (const float*)d_in[3];
  const float* wd = (const float*)d_in[4];
  float* out = (float*)d_out;
  char* ws = (char*)d_ws;

  ushort* xb     = (ushort*)(ws + XB_OFF);
  ushort* gbuf   = (ushort*)(ws + GBUF_OFF);
  ushort* ubuf   = (ushort*)(ws + UBUF_OFF);
  float*  topkw  = (float*)(ws + TKW_OFF);
  int*    topki  = (int*)(ws + TKI_OFF);
  int*    rows   = (int*)(ws + ROWS_OFF);
  float*  wts    = (float*)(ws + WTS_OFF);
  int*    offs   = (int*)(ws + OFFS_OFF);
  float*  logits = (float*)(ws + LOGIT_OFF);
  int*    counts = (int*)(ws + CNT_OFF);
  int*    fill   = (int*)(ws + FILL_OFF);
  int*    tlist  = (int*)(ws + TLIST_OFF);

  hipMemsetAsync(ws + ZERO_OFF, 0, ZERO_SZ, stream);
  hipMemsetAsync(d_out, 0, (size_t)out_size * sizeof(float), stream);

  convert_x_kernel<<<2048, 256, 0, stream>>>(x, xb);
  router_gemm<<<dim3(32, 8), 256, 0, stream>>>(x, wr, logits);
  topk_kernel<<<8, 256, 0, stream>>>(logits, topkw, topki, counts);
  prefix_kernel<<<1, 64, 0, stream>>>(counts, offs, tlist);
  scatter_kernel<<<32, 256, 0, stream>>>(topki, topkw, offs, fill, rows, wts);
  guv_kernel<<<dim3(6, MAXT), 512, 0, stream>>>(xb, wg, wu, rows, counts, offs, tlist, gbuf, ubuf);
  fuse_kernel<<<NSLOT, 192, 0, stream>>>(gbuf, ubuf, wts);
  down_kernel<<<dim3(8, MAXT), 512, 0, stream>>>(gbuf, wd, rows, counts, offs, tlist, out);
}